// Round 13
// baseline (260.855 us; speedup 1.0000x reference)
//
#include <hip/hip_runtime.h>
#include <stdint.h>

typedef _Float16 f16;
typedef f16 f16x4 __attribute__((ext_vector_type(4)));
typedef f16 f16x8 __attribute__((ext_vector_type(8)));
typedef float f32x4 __attribute__((ext_vector_type(4)));

constexpr float SCALE = 0.08838834764831845f; // 1/sqrt(128)

__device__ __forceinline__ void glds16(const void* g, void* l) {
  __builtin_amdgcn_global_load_lds(
      (const __attribute__((address_space(1))) void*)g,
      (__attribute__((address_space(3))) void*)l, 16, 0, 0);
}
__device__ __forceinline__ void glds4(const void* g, void* l) {
  __builtin_amdgcn_global_load_lds(
      (const __attribute__((address_space(1))) void*)g,
      (__attribute__((address_space(3))) void*)l, 4, 0, 0);
}

// ---------------- projection:
// q = f1*W1^T + b1 (f16), k = f2*W2^T + b2 (f16); f1t/f2t = transposed features
__global__ __launch_bounds__(256) void proj_kernel(
    const float* __restrict__ f1, const float* __restrict__ f2,
    const float* __restrict__ W1, const float* __restrict__ b1,
    const float* __restrict__ W2, const float* __restrict__ b2,
    f16* __restrict__ q_h, f16* __restrict__ k_h,
    f16* __restrict__ f1t, f16* __restrict__ f2t)
{
  __shared__ f16 a_lds[128 * 128];
  __shared__ f16 w_lds[128 * 128];

  const int tid = threadIdx.x;
  const int blk = blockIdx.x;
  const bool qside = blk < 512;
  const float* feat = qside ? f1 : f2;
  const float* W    = qside ? W1 : W2;
  const float* bias = qside ? b1 : b2;
  f16* op = qside ? q_h : k_h;
  f16* ft = qside ? f1t : f2t;
  const size_t row0 = (size_t)(qside ? blk : blk - 512) * 128;

  for (int it = 0; it < 16; ++it) {
    int u = tid + it * 256;
    int r = u >> 5;
    int c4 = (u & 31) * 4;
    float4 v = *(const float4*)&feat[(row0 + r) * 128 + c4];
    f16x4 h4 = { (f16)v.x, (f16)v.y, (f16)v.z, (f16)v.w };
    int adr = r * 128 + ((((c4 >> 3) ^ (r & 7)) << 3) | (c4 & 7));
    *(f16x4*)&a_lds[adr] = h4;
    float4 wv = *(const float4*)&W[r * 128 + c4];
    f16x4 wh = { (f16)wv.x, (f16)wv.y, (f16)wv.z, (f16)wv.w };
    *(f16x4*)&w_lds[adr] = wh;
  }
  __syncthreads();

  const int w = tid >> 6, l = tid & 63, lam = l & 15, g = l >> 4;
  f32x4 acc[2][8] = {};
#pragma unroll
  for (int kc = 0; kc < 4; ++kc) {
    f16x8 a[2];
#pragma unroll
    for (int rf = 0; rf < 2; ++rf) {
      int ar = w * 32 + rf * 16 + lam;
      a[rf] = *(const f16x8*)&a_lds[ar * 128 + (((4 * kc + g) ^ (ar & 7)) << 3)];
    }
#pragma unroll
    for (int cf = 0; cf < 8; ++cf) {
      int br = cf * 16 + lam;
      f16x8 bfr = *(const f16x8*)&w_lds[br * 128 + (((4 * kc + g) ^ (br & 7)) << 3)];
      acc[0][cf] = __builtin_amdgcn_mfma_f32_16x16x32_f16(a[0], bfr, acc[0][cf], 0, 0, 0);
      acc[1][cf] = __builtin_amdgcn_mfma_f32_16x16x32_f16(a[1], bfr, acc[1][cf], 0, 0, 0);
    }
  }
#pragma unroll
  for (int cf = 0; cf < 8; ++cf) {
    int col = cf * 16 + lam;
    float bv = bias[col];
#pragma unroll
    for (int rf = 0; rf < 2; ++rf)
#pragma unroll
      for (int i = 0; i < 4; ++i) {
        size_t grow = row0 + w * 32 + rf * 16 + g * 4 + i;
        op[grow * 128 + col] = (f16)(acc[rf][cf][i] + bv);
      }
  }

  { // transposed feature write: ft[b][f][l]
    const int b = (int)(row0 >> 10);
    const int l0 = (int)(row0 & 1023);
    const int f = tid >> 1;
    const int half = tid & 1;
    f16 buf[64];
#pragma unroll
    for (int j = 0; j < 64; ++j) {
      int r = half * 64 + j;
      buf[j] = a_lds[r * 128 + ((((f >> 3) ^ (r & 7)) << 3) | (f & 7))];
    }
    f16* dst = ft + ((size_t)b * 128 + f) * 1024 + l0 + half * 64;
#pragma unroll
    for (int c = 0; c < 8; ++c)
      *(f16x8*)&dst[c * 8] = *(const f16x8*)&buf[c * 8];
  }
}

// ---------------- flash attention pass, QBLK=128, grid 512 (2/CU exact)
// Permuted bit layout: element e -> word (e>>11)*64 + ((e>>2)&63),
//                                   bit ((e>>8)&7)*4 + (e&3)
// PASS 0: prologue packs own 128-row mask slab (64 chunks x 2048) into
//         LDS mball[64][65] (all 16 tiles) + writes global bits for pass 1.
// PASS 1: per-tile glds4 stage of bits (r12-verified path).
template <int PASS>
__global__ __launch_bounds__(256, 2) void attn_kernel(
    const f16* __restrict__ Qh, const f16* __restrict__ Kh,
    const f16* __restrict__ Vt,
    const int* __restrict__ mask, uint32_t* __restrict__ bits,
    float* __restrict__ outp)
{
  __shared__ f16 k_lds[64 * 128];
  __shared__ f16 v_lds[128 * 64];       // [feature][kv], chunk-XOR swizzled
  __shared__ f16 p_lds[8 * 16 * 72];    // per (wave, quadrant) P slice
  __shared__ uint32_t mball[(PASS == 0) ? 64 * 65 : 1024];

  const int tid = threadIdx.x;
  const int u = blockIdx.x;             // 512 blocks
  const int qt = (u >> 3) & 7;
  const int b = ((u >> 6) << 3) | (u & 7);
  const int w = tid >> 6, l = tid & 63, lam = l & 15, g = l >> 4;
  const size_t batch_row = (size_t)b << 10;

  // Q fragments in registers: 2 quadrants x 4 k-chunks (one-time)
  f16x8 qf[2][4];
#pragma unroll
  for (int qd = 0; qd < 2; ++qd) {
    const f16* qbase = Qh + (batch_row + qt * 128 + w * 32 + qd * 16 + lam) * 128;
#pragma unroll
    for (int kc = 0; kc < 4; ++kc) qf[qd][kc] = *(const f16x8*)&qbase[kc * 32 + g * 8];
  }

  if constexpr (PASS == 0) {
    // ---- slab pack prologue: wave w owns chunks w*16..w*16+15
    const int cbase = (int)(batch_row >> 1) + qt * 64; // global chunk base
    for (int cc = 0; cc < 16; ++cc) {
      const int c_local = w * 16 + cc;
      const int4* src = (const int4*)(mask + (size_t)(cbase + c_local) * 2048) + l;
      uint32_t word = 0;
#pragma unroll
      for (int it = 0; it < 8; ++it) {
        int4 v = src[it * 64];
        uint32_t nib = (v.x ? 1u : 0u) | (v.y ? 2u : 0u) |
                       (v.z ? 4u : 0u) | (v.w ? 8u : 0u);
        word |= nib << (it * 4);
      }
      mball[c_local * 65 + l] = word;
      bits[(size_t)(cbase + c_local) * 64 + l] = word;
    }
  }

  f32x4 acc[2][8] = {};
  float mrun[2][4], lrun[2][4];
#pragma unroll
  for (int qd = 0; qd < 2; ++qd)
#pragma unroll
    for (int i = 0; i < 4; ++i) { mrun[qd][i] = -__builtin_inff(); lrun[qd][i] = 0.f; }

  const f16* vtb = Vt + ((size_t)b << 17);

  for (int kt = 0; kt < 16; ++kt) {
    const int kb = kt * 64;
    __syncthreads();
    { // stage K tile (64 rows x 128, swizzled via pre-swizzled source)
      const f16* kbase = Kh + (batch_row + kb) * 128;
#pragma unroll
      for (int it = 0; it < 4; ++it) {
        int slot0 = (w * 4 + it) * 64;
        int i = slot0 + l;
        int r = i >> 4, ch = i & 15;
        glds16(kbase + r * 128 + ((ch ^ (r & 7)) << 3), &k_lds[slot0 * 8]);
      }
    }
    { // stage V^T tile (128 feature-rows x 64 kv, swizzled)
#pragma unroll
      for (int it = 0; it < 4; ++it) {
        int slot0 = (w * 4 + it) * 64;
        int i = slot0 + l;
        int r = i >> 3, ch = i & 7;
        glds16(vtb + r * 1024 + kb + ((ch ^ (r & 7)) << 3), &v_lds[slot0 * 8]);
      }
    }
    if constexpr (PASS == 1) { // stage permuted bit-words (r12-verified)
      const uint32_t* bw = bits + ((batch_row + kb) >> 1) * 64 + (qt & 1) * 32;
#pragma unroll
      for (int t = 0; t < 4; ++t) {
        int p = (w * 4 + t) * 64 + l;
        glds4(bw + (p >> 5) * 64 + ((p & 31) ^ (((p >> 5) & 7) << 2)),
              &mball[(w * 4 + t) * 64]);
      }
    }
    __syncthreads();

    // ---- two quadrants: QK^T + softmax + P store ----
#pragma unroll
    for (int qd = 0; qd < 2; ++qd) {
      f32x4 sv[4] = {};
      __builtin_amdgcn_s_setprio(1);
#pragma unroll
      for (int kc = 0; kc < 4; ++kc) {
#pragma unroll
        for (int cf = 0; cf < 4; ++cf) {
          int br = cf * 16 + lam;
          f16x8 bk = *(const f16x8*)&k_lds[br * 128 + (((4 * kc + g) ^ (br & 7)) << 3)];
          sv[cf] = __builtin_amdgcn_mfma_f32_16x16x32_f16(qf[qd][kc], bk, sv[cf], 0, 0, 0);
        }
      }
      __builtin_amdgcn_s_setprio(0);

      // gather mask bits from permuted layout
      uint32_t mk = 0;
      if constexpr (PASS == 0) {
        const int so = ((kt >> 2) << 2) + (lam & 3);
#pragma unroll
        for (int cf = 0; cf < 4; ++cf)
#pragma unroll
          for (int ih = 0; ih < 2; ++ih) {
            int rp = w * 16 + qd * 8 + g * 2 + ih;
            int sp = (kt & 3) * 16 + cf * 4 + (lam >> 2);
            uint32_t wd = mball[rp * 65 + sp];
            mk |= ((wd >> so) & 1u) << (cf * 4 + ih * 2);
            mk |= ((wd >> (16 + so)) & 1u) << (cf * 4 + ih * 2 + 1);
          }
      } else {
        const int shift = ((lam & 1) << 4) + ((qt >> 1) << 2);
        const int s1 = w * 8 + qd * 4 + g;
#pragma unroll
        for (int cf = 0; cf < 4; ++cf) {
          int rp = cf * 8 + (lam >> 1);
          uint32_t wd = mball[rp * 32 + (s1 ^ ((rp & 7) << 2))];
          mk |= ((wd >> shift) & 15u) << (cf * 4);
        }
      }

      float mrow4[4];
#pragma unroll
      for (int i = 0; i < 4; ++i) mrow4[i] = -1e30f;
#pragma unroll
      for (int cf = 0; cf < 4; ++cf)
#pragma unroll
        for (int i = 0; i < 4; ++i) {
          float v = sv[cf][i] * SCALE;
          sv[cf][i] = v;
          mrow4[i] = fmaxf(mrow4[i], ((mk >> (cf * 4 + i)) & 1u) ? v : -1e30f);
        }
#pragma unroll
      for (int d = 1; d <= 8; d <<= 1)
#pragma unroll
        for (int i = 0; i < 4; ++i)
          mrow4[i] = fmaxf(mrow4[i], __shfl_xor(mrow4[i], d, 64));

      float sf[4], lsum[4];
#pragma unroll
      for (int i = 0; i < 4; ++i) {
        float mn = fmaxf(mrun[qd][i], mrow4[i]);
        sf[i] = __expf(mrun[qd][i] - mn);
        mrun[qd][i] = mn;
        lsum[i] = 0.f;
      }
      f16* pslice = &p_lds[(w * 2 + qd) * 1152];
#pragma unroll
      for (int cf = 0; cf < 4; ++cf)
#pragma unroll
        for (int i = 0; i < 4; ++i) {
          float p = ((mk >> (cf * 4 + i)) & 1u) ? __expf(sv[cf][i] - mrun[qd][i]) : 0.f;
          lsum[i] += p;
          int row = g * 4 + i;
          int cchunk = 2 * cf + (lam >> 3);
          pslice[row * 72 + (((cchunk ^ (row & 7)) << 3) | (lam & 7))] = (f16)p;
        }
#pragma unroll
      for (int d = 1; d <= 8; d <<= 1)
#pragma unroll
        for (int i = 0; i < 4; ++i)
          lsum[i] += __shfl_xor(lsum[i], d, 64);
#pragma unroll
      for (int i = 0; i < 4; ++i) lrun[qd][i] = lrun[qd][i] * sf[i] + lsum[i];
#pragma unroll
      for (int nf = 0; nf < 8; ++nf)
#pragma unroll
        for (int i = 0; i < 4; ++i) acc[qd][nf][i] *= sf[i];
    }

    // ---- PV for both quadrants, sharing each V fragment ----
    __builtin_amdgcn_s_setprio(1);
#pragma unroll
    for (int kc2 = 0; kc2 < 2; ++kc2) {
      f16x8 ap0 = *(const f16x8*)&p_lds[(w * 2 + 0) * 1152 + lam * 72 + (((4 * kc2 + g) ^ (lam & 7)) << 3)];
      f16x8 ap1 = *(const f16x8*)&p_lds[(w * 2 + 1) * 1152 + lam * 72 + (((4 * kc2 + g) ^ (lam & 7)) << 3)];
#pragma unroll
      for (int nf = 0; nf < 8; ++nf) {
        int vr = nf * 16 + lam;
        f16x8 bv = *(const f16x8*)&v_lds[vr * 64 + (((kc2 * 4 + g) ^ (vr & 7)) << 3)];
        acc[0][nf] = __builtin_amdgcn_mfma_f32_16x16x32_f16(ap0, bv, acc[0][nf], 0, 0, 0);
        acc[1][nf] = __builtin_amdgcn_mfma_f32_16x16x32_f16(ap1, bv, acc[1][nf], 0, 0, 0);
      }
    }
    __builtin_amdgcn_s_setprio(0);
  }

  // epilogue
#pragma unroll
  for (int qd = 0; qd < 2; ++qd) {
    float inv[4];
#pragma unroll
    for (int i = 0; i < 4; ++i) inv[i] = (lrun[qd][i] > 0.f) ? 1.f / lrun[qd][i] : 0.f;
    const size_t orow0 = batch_row + (size_t)qt * 128 + w * 32 + qd * 16;
#pragma unroll
    for (int nf = 0; nf < 8; ++nf)
#pragma unroll
      for (int i = 0; i < 4; ++i)
        outp[(orow0 + g * 4 + i) * 128 + nf * 16 + lam] = acc[qd][nf][i] * inv[i];
  }
}

extern "C" void kernel_launch(void* const* d_in, const int* in_sizes, int n_in,
                              void* d_out, int out_size, void* d_ws, size_t ws_size,
                              hipStream_t stream) {
  const float* f1 = (const float*)d_in[0];
  const float* f2 = (const float*)d_in[1];
  const int* mask = (const int*)d_in[2];
  const float* W1 = (const float*)d_in[3];
  const float* b1 = (const float*)d_in[4];
  const float* W2 = (const float*)d_in[5];
  const float* b2 = (const float*)d_in[6];
  float* out = (float*)d_out;

  // ws: q_h(16MiB) k_h(16MiB) f1t(16MiB) bits(8MiB) = 56 MiB
  if (ws_size < (size_t)3 * 8388608 * sizeof(f16) + 8388608) return;

  f16* q_h = (f16*)d_ws;
  f16* k_h = q_h + 8388608;
  f16* f1t = k_h + 8388608;
  uint32_t* bits = (uint32_t*)(f1t + 8388608);
  // f2t lives in the out1 region of d_out: proj writes it; attn0 reads it;
  // attn1 overwrites that region afterwards (stream-ordered).
  f16* f2t = (f16*)d_out;

  proj_kernel<<<1024, 256, 0, stream>>>(f1, f2, W1, b1, W2, b2, q_h, k_h, f1t, f2t);
  // out layout: out1 [B,L2,F1] first, then out2 [B,L1,F2]
  attn_kernel<0><<<512, 256, 0, stream>>>(q_h, k_h, f2t, mask, bits,
                                          out + 8388608);                 // out2
  attn_kernel<1><<<512, 256, 0, stream>>>(k_h, q_h, f1t, nullptr, bits,
                                          out);                           // out1
}

// Round 14
// 248.573 us; speedup vs baseline: 1.0494x; 1.0494x over previous
//
#include <hip/hip_runtime.h>
#include <stdint.h>

typedef _Float16 f16;
typedef f16 f16x4 __attribute__((ext_vector_type(4)));
typedef f16 f16x8 __attribute__((ext_vector_type(8)));
typedef float f32x4 __attribute__((ext_vector_type(4)));
typedef int i32x4 __attribute__((ext_vector_type(4)));

constexpr float SCALE = 0.08838834764831845f; // 1/sqrt(128)

__device__ __forceinline__ void glds16(const void* g, void* l) {
  __builtin_amdgcn_global_load_lds(
      (const __attribute__((address_space(1))) void*)g,
      (__attribute__((address_space(3))) void*)l, 16, 0, 0);
}
__device__ __forceinline__ void glds4(const void* g, void* l) {
  __builtin_amdgcn_global_load_lds(
      (const __attribute__((address_space(1))) void*)g,
      (__attribute__((address_space(3))) void*)l, 4, 0, 0);
}

// ---------------- mask pack v4 + NONTEMPORAL loads (no L3 allocation ->
// no dirty-line eviction/writeback tax). Permuted layout:
//   element e -> word (e>>11)*64 + ((e>>2)&63), bit ((e>>8)&7)*4 + (e&3)
__global__ __launch_bounds__(256) void pack_kernel(
    const int* __restrict__ mask, uint32_t* __restrict__ bits)
{
  const int wv = blockIdx.x * 4 + (threadIdx.x >> 6); // 8192 waves
  const int lane = threadIdx.x & 63;
#pragma unroll 2
  for (int cc = 0; cc < 4; ++cc) {
    const size_t c = (size_t)wv * 4 + cc;
    const i32x4* src = (const i32x4*)(mask + c * 2048) + lane;
    uint32_t word = 0;
#pragma unroll
    for (int it = 0; it < 8; ++it) {
      i32x4 v = __builtin_nontemporal_load(src + it * 64);
      uint32_t nib = (v[0] ? 1u : 0u) | (v[1] ? 2u : 0u) |
                     (v[2] ? 4u : 0u) | (v[3] ? 8u : 0u);
      word |= nib << (it * 4);
    }
    bits[c * 64 + lane] = word;
  }
}

// ---------------- projection (NT feature loads):
// q = f1*W1^T + b1 (f16), k = f2*W2^T + b2 (f16); f1t/f2t = transposed features
__global__ __launch_bounds__(256) void proj_kernel(
    const float* __restrict__ f1, const float* __restrict__ f2,
    const float* __restrict__ W1, const float* __restrict__ b1,
    const float* __restrict__ W2, const float* __restrict__ b2,
    f16* __restrict__ q_h, f16* __restrict__ k_h,
    f16* __restrict__ f1t, f16* __restrict__ f2t)
{
  __shared__ f16 a_lds[128 * 128];
  __shared__ f16 w_lds[128 * 128];

  const int tid = threadIdx.x;
  const int blk = blockIdx.x;
  const bool qside = blk < 512;
  const float* feat = qside ? f1 : f2;
  const float* W    = qside ? W1 : W2;
  const float* bias = qside ? b1 : b2;
  f16* op = qside ? q_h : k_h;
  f16* ft = qside ? f1t : f2t;
  const size_t row0 = (size_t)(qside ? blk : blk - 512) * 128;

  for (int it = 0; it < 16; ++it) {
    int u = tid + it * 256;
    int r = u >> 5;
    int c4 = (u & 31) * 4;
    f32x4 v = __builtin_nontemporal_load(
        (const f32x4*)&feat[(row0 + r) * 128 + c4]);
    f16x4 h4 = { (f16)v[0], (f16)v[1], (f16)v[2], (f16)v[3] };
    int adr = r * 128 + ((((c4 >> 3) ^ (r & 7)) << 3) | (c4 & 7));
    *(f16x4*)&a_lds[adr] = h4;
    float4 wv = *(const float4*)&W[r * 128 + c4];
    f16x4 wh = { (f16)wv.x, (f16)wv.y, (f16)wv.z, (f16)wv.w };
    *(f16x4*)&w_lds[adr] = wh;
  }
  __syncthreads();

  const int w = tid >> 6, l = tid & 63, lam = l & 15, g = l >> 4;
  f32x4 acc[2][8] = {};
#pragma unroll
  for (int kc = 0; kc < 4; ++kc) {
    f16x8 a[2];
#pragma unroll
    for (int rf = 0; rf < 2; ++rf) {
      int ar = w * 32 + rf * 16 + lam;
      a[rf] = *(const f16x8*)&a_lds[ar * 128 + (((4 * kc + g) ^ (ar & 7)) << 3)];
    }
#pragma unroll
    for (int cf = 0; cf < 8; ++cf) {
      int br = cf * 16 + lam;
      f16x8 bfr = *(const f16x8*)&w_lds[br * 128 + (((4 * kc + g) ^ (br & 7)) << 3)];
      acc[0][cf] = __builtin_amdgcn_mfma_f32_16x16x32_f16(a[0], bfr, acc[0][cf], 0, 0, 0);
      acc[1][cf] = __builtin_amdgcn_mfma_f32_16x16x32_f16(a[1], bfr, acc[1][cf], 0, 0, 0);
    }
  }
#pragma unroll
  for (int cf = 0; cf < 8; ++cf) {
    int col = cf * 16 + lam;
    float bv = bias[col];
#pragma unroll
    for (int rf = 0; rf < 2; ++rf)
#pragma unroll
      for (int i = 0; i < 4; ++i) {
        size_t grow = row0 + w * 32 + rf * 16 + g * 4 + i;
        op[grow * 128 + col] = (f16)(acc[rf][cf][i] + bv);
      }
  }

  { // transposed feature write: ft[b][f][l]
    const int b = (int)(row0 >> 10);
    const int l0 = (int)(row0 & 1023);
    const int f = tid >> 1;
    const int half = tid & 1;
    f16 buf[64];
#pragma unroll
    for (int j = 0; j < 64; ++j) {
      int r = half * 64 + j;
      buf[j] = a_lds[r * 128 + ((((f >> 3) ^ (r & 7)) << 3) | (f & 7))];
    }
    f16* dst = ft + ((size_t)b * 128 + f) * 1024 + l0 + half * 64;
#pragma unroll
    for (int c = 0; c < 8; ++c)
      *(f16x8*)&dst[c * 8] = *(const f16x8*)&buf[c * 8];
  }
}

// ---------------- flash attention pass, QBLK=128, grid 512 (2/CU exact)
// Consumes the PERMUTED bit image (see pack_kernel comment). r12-verified.
template <int PASS>
__global__ __launch_bounds__(256, 2) void attn_kernel(
    const f16* __restrict__ Qh, const f16* __restrict__ Kh,
    const f16* __restrict__ Vt, const uint32_t* __restrict__ bits,
    float* __restrict__ outp)
{
  __shared__ f16 k_lds[64 * 128];
  __shared__ f16 v_lds[128 * 64];       // [feature][kv], chunk-XOR swizzled
  __shared__ f16 p_lds[8 * 16 * 72];    // per (wave, quadrant) P slice
  __shared__ uint32_t mb2[1024];        // permuted bit-words tile (4 KB)

  const int tid = threadIdx.x;
  const int u = blockIdx.x;             // 512 blocks
  const int qt = (u >> 3) & 7;
  const int b = ((u >> 6) << 3) | (u & 7);
  const int w = tid >> 6, l = tid & 63, lam = l & 15, g = l >> 4;
  const size_t batch_row = (size_t)b << 10;

  // Q fragments in registers: 2 quadrants x 4 k-chunks (one-time)
  f16x8 qf[2][4];
#pragma unroll
  for (int qd = 0; qd < 2; ++qd) {
    const f16* qbase = Qh + (batch_row + qt * 128 + w * 32 + qd * 16 + lam) * 128;
#pragma unroll
    for (int kc = 0; kc < 4; ++kc) qf[qd][kc] = *(const f16x8*)&qbase[kc * 32 + g * 8];
  }

  f32x4 acc[2][8] = {};
  float mrun[2][4], lrun[2][4];
#pragma unroll
  for (int qd = 0; qd < 2; ++qd)
#pragma unroll
    for (int i = 0; i < 4; ++i) { mrun[qd][i] = -__builtin_inff(); lrun[qd][i] = 0.f; }

  const f16* vtb = Vt + ((size_t)b << 17);

  for (int kt = 0; kt < 16; ++kt) {
    const int kb = kt * 64;
    __syncthreads();
    { // stage K tile (64 rows x 128, swizzled via pre-swizzled source)
      const f16* kbase = Kh + (batch_row + kb) * 128;
#pragma unroll
      for (int it = 0; it < 4; ++it) {
        int slot0 = (w * 4 + it) * 64;
        int i = slot0 + l;
        int r = i >> 4, ch = i & 15;
        glds16(kbase + r * 128 + ((ch ^ (r & 7)) << 3), &k_lds[slot0 * 8]);
      }
    }
    { // stage V^T tile (128 feature-rows x 64 kv, swizzled)
#pragma unroll
      for (int it = 0; it < 4; ++it) {
        int slot0 = (w * 4 + it) * 64;
        int i = slot0 + l;
        int r = i >> 3, ch = i & 7;
        glds16(vtb + r * 1024 + kb + ((ch ^ (r & 7)) << 3), &v_lds[slot0 * 8]);
      }
    }
    { // stage permuted bit-words: 1024 words, XOR-swizzled (src-permuted)
      if constexpr (PASS == 0) {
        const uint32_t* bw = bits + ((batch_row + qt * 128) >> 1) * 64 + (kt & 3) * 16;
#pragma unroll
        for (int t = 0; t < 4; ++t) {
          int p = (w * 4 + t) * 64 + l;
          glds4(bw + (p >> 4) * 64 + ((p & 15) ^ (((p >> 4) & 3) << 2)),
                &mb2[(w * 4 + t) * 64]);
        }
      } else {
        const uint32_t* bw = bits + ((batch_row + kb) >> 1) * 64 + (qt & 1) * 32;
#pragma unroll
        for (int t = 0; t < 4; ++t) {
          int p = (w * 4 + t) * 64 + l;
          glds4(bw + (p >> 5) * 64 + ((p & 31) ^ (((p >> 5) & 7) << 2)),
                &mb2[(w * 4 + t) * 64]);
        }
      }
    }
    __syncthreads();

    // ---- two quadrants: QK^T + softmax + P store ----
#pragma unroll
    for (int qd = 0; qd < 2; ++qd) {
      f32x4 sv[4] = {};
      __builtin_amdgcn_s_setprio(1);
#pragma unroll
      for (int kc = 0; kc < 4; ++kc) {
#pragma unroll
        for (int cf = 0; cf < 4; ++cf) {
          int br = cf * 16 + lam;
          f16x8 bk = *(const f16x8*)&k_lds[br * 128 + (((4 * kc + g) ^ (br & 7)) << 3)];
          sv[cf] = __builtin_amdgcn_mfma_f32_16x16x32_f16(qf[qd][kc], bk, sv[cf], 0, 0, 0);
        }
      }
      __builtin_amdgcn_s_setprio(0);

      // gather mask bits from permuted layout
      uint32_t mk = 0;
      if constexpr (PASS == 0) {
        const int so = ((kt >> 2) << 2) + (lam & 3);
#pragma unroll
        for (int cf = 0; cf < 4; ++cf)
#pragma unroll
          for (int ih = 0; ih < 2; ++ih) {
            int rp = w * 16 + qd * 8 + g * 2 + ih;
            int s  = cf * 4 + (lam >> 2);
            uint32_t wd = mb2[rp * 16 + (s ^ ((rp & 3) << 2))];
            mk |= ((wd >> so) & 1u) << (cf * 4 + ih * 2);
            mk |= ((wd >> (16 + so)) & 1u) << (cf * 4 + ih * 2 + 1);
          }
      } else {
        const int shift = ((lam & 1) << 4) + ((qt >> 1) << 2);
        const int s1 = w * 8 + qd * 4 + g;
#pragma unroll
        for (int cf = 0; cf < 4; ++cf) {
          int rp = cf * 8 + (lam >> 1);
          uint32_t wd = mb2[rp * 32 + (s1 ^ ((rp & 7) << 2))];
          mk |= ((wd >> shift) & 15u) << (cf * 4);
        }
      }

      float mrow4[4];
#pragma unroll
      for (int i = 0; i < 4; ++i) mrow4[i] = -1e30f;
#pragma unroll
      for (int cf = 0; cf < 4; ++cf)
#pragma unroll
        for (int i = 0; i < 4; ++i) {
          float v = sv[cf][i] * SCALE;
          sv[cf][i] = v;
          mrow4[i] = fmaxf(mrow4[i], ((mk >> (cf * 4 + i)) & 1u) ? v : -1e30f);
        }
#pragma unroll
      for (int d = 1; d <= 8; d <<= 1)
#pragma unroll
        for (int i = 0; i < 4; ++i)
          mrow4[i] = fmaxf(mrow4[i], __shfl_xor(mrow4[i], d, 64));

      float sf[4], lsum[4];
#pragma unroll
      for (int i = 0; i < 4; ++i) {
        float mn = fmaxf(mrun[qd][i], mrow4[i]);
        sf[i] = __expf(mrun[qd][i] - mn);
        mrun[qd][i] = mn;
        lsum[i] = 0.f;
      }
      f16* pslice = &p_lds[(w * 2 + qd) * 1152];
#pragma unroll
      for (int cf = 0; cf < 4; ++cf)
#pragma unroll
        for (int i = 0; i < 4; ++i) {
          float p = ((mk >> (cf * 4 + i)) & 1u) ? __expf(sv[cf][i] - mrun[qd][i]) : 0.f;
          lsum[i] += p;
          int row = g * 4 + i;
          int cchunk = 2 * cf + (lam >> 3);
          pslice[row * 72 + (((cchunk ^ (row & 7)) << 3) | (lam & 7))] = (f16)p;
        }
#pragma unroll
      for (int d = 1; d <= 8; d <<= 1)
#pragma unroll
        for (int i = 0; i < 4; ++i)
          lsum[i] += __shfl_xor(lsum[i], d, 64);
#pragma unroll
      for (int i = 0; i < 4; ++i) lrun[qd][i] = lrun[qd][i] * sf[i] + lsum[i];
#pragma unroll
      for (int nf = 0; nf < 8; ++nf)
#pragma unroll
        for (int i = 0; i < 4; ++i) acc[qd][nf][i] *= sf[i];
    }

    // ---- PV for both quadrants, sharing each V fragment ----
    __builtin_amdgcn_s_setprio(1);
#pragma unroll
    for (int kc2 = 0; kc2 < 2; ++kc2) {
      f16x8 ap0 = *(const f16x8*)&p_lds[(w * 2 + 0) * 1152 + lam * 72 + (((4 * kc2 + g) ^ (lam & 7)) << 3)];
      f16x8 ap1 = *(const f16x8*)&p_lds[(w * 2 + 1) * 1152 + lam * 72 + (((4 * kc2 + g) ^ (lam & 7)) << 3)];
#pragma unroll
      for (int nf = 0; nf < 8; ++nf) {
        int vr = nf * 16 + lam;
        f16x8 bv = *(const f16x8*)&v_lds[vr * 64 + (((kc2 * 4 + g) ^ (vr & 7)) << 3)];
        acc[0][nf] = __builtin_amdgcn_mfma_f32_16x16x32_f16(ap0, bv, acc[0][nf], 0, 0, 0);
        acc[1][nf] = __builtin_amdgcn_mfma_f32_16x16x32_f16(ap1, bv, acc[1][nf], 0, 0, 0);
      }
    }
    __builtin_amdgcn_s_setprio(0);
  }

  // epilogue: NT stores (outputs are never re-read; keep L3 clean)
#pragma unroll
  for (int qd = 0; qd < 2; ++qd) {
    float inv[4];
#pragma unroll
    for (int i = 0; i < 4; ++i) inv[i] = (lrun[qd][i] > 0.f) ? 1.f / lrun[qd][i] : 0.f;
    const size_t orow0 = batch_row + (size_t)qt * 128 + w * 32 + qd * 16;
#pragma unroll
    for (int nf = 0; nf < 8; ++nf)
#pragma unroll
      for (int i = 0; i < 4; ++i)
        __builtin_nontemporal_store(acc[qd][nf][i] * inv[i],
            &outp[(orow0 + g * 4 + i) * 128 + nf * 16 + lam]);
  }
}

extern "C" void kernel_launch(void* const* d_in, const int* in_sizes, int n_in,
                              void* d_out, int out_size, void* d_ws, size_t ws_size,
                              hipStream_t stream) {
  const float* f1 = (const float*)d_in[0];
  const float* f2 = (const float*)d_in[1];
  const int* mask = (const int*)d_in[2];
  const float* W1 = (const float*)d_in[3];
  const float* b1 = (const float*)d_in[4];
  const float* W2 = (const float*)d_in[5];
  const float* b2 = (const float*)d_in[6];
  float* out = (float*)d_out;

  // ws: q_h(16MiB) k_h(16MiB) f1t(16MiB) bits(8MiB) = 56 MiB
  if (ws_size < (size_t)3 * 8388608 * sizeof(f16) + 8388608) return;

  f16* q_h = (f16*)d_ws;
  f16* k_h = q_h + 8388608;
  f16* f1t = k_h + 8388608;
  uint32_t* bits = (uint32_t*)(f1t + 8388608);
  // f2t lives in the out1 region of d_out: proj writes it; attn0 reads it;
  // attn1 overwrites that region afterwards (stream-ordered).
  f16* f2t = (f16*)d_out;

  proj_kernel<<<1024, 256, 0, stream>>>(f1, f2, W1, b1, W2, b2, q_h, k_h, f1t, f2t);
  pack_kernel<<<2048, 256, 0, stream>>>(mask, bits);
  // out layout: out1 [B,L2,F1] first, then out2 [B,L1,F2]
  attn_kernel<0><<<512, 256, 0, stream>>>(q_h, k_h, f2t, bits, out + 8388608); // out2
  attn_kernel<1><<<512, 256, 0, stream>>>(k_h, q_h, f1t, bits, out);           // out1
}